// Round 3
// baseline (227.938 us; speedup 1.0000x reference)
//
#include <hip/hip_runtime.h>
#include <math.h>

#define B_    4
#define SEQ_  2048
#define S_    128
#define L_    2304          // SEQ + 2*S
#define DIN   512
#define DK    64
#define NEGINF (-1e30f)
#define SCALE 0.125f
#define NCOLS 2176
#define NMID  8192          // B_*SEQ_
#define NEDGE 1024          // B_*2*S_
#define LE    2304          // edge De row length

typedef _Float16 f16;
typedef __attribute__((ext_vector_type(8))) _Float16 half8;
typedef __attribute__((ext_vector_type(4))) float f32x4;

union U4 { uint4 u; f16 h[8]; };

// ---------------------------------------------------------------------------
// k_wsplit: pre-split 9 W matrices into fp16 hi/lo (transposed) + cope split.
// grid (8, 10) x 256. mat==9: cope (64x128) -> copesp[p][hi d | lo d].
// ---------------------------------------------------------------------------
__global__ __launch_bounds__(256) void k_wsplit(
    const float* __restrict__ Wq,  const float* __restrict__ Wk,  const float* __restrict__ Wv,
    const float* __restrict__ Wqs, const float* __restrict__ Wks, const float* __restrict__ Wvs,
    const float* __restrict__ Wqe, const float* __restrict__ Wke, const float* __restrict__ Wve,
    const float* __restrict__ cope,
    f16* __restrict__ Wsp, f16* __restrict__ copesp)
{
    __shared__ float xs[64 * 68];
    const int kt  = blockIdx.x;
    const int mat = blockIdx.y;
    const int tid = threadIdx.x;

    if (mat == 9) {
        if (kt != 0) return;
        for (int half = 0; half < 2; ++half) {
            #pragma unroll
            for (int i = 0; i < 4; ++i) {
                int g = tid + 256 * i;          // 64 d x 16 float4
                int d = g >> 4, p4 = g & 15;
                *(float4*)(xs + d * 68 + p4 * 4) =
                    *(const float4*)(cope + (size_t)d * 128 + half * 64 + p4 * 4);
            }
            __syncthreads();
            if (tid < 128) {
                int pp = tid & 63, hf = tid >> 6;   // 2 halves of d
                int d0 = hf * 32;
                for (int j = 0; j < 32; ++j) {
                    float v = xs[(d0 + j) * 68 + pp];
                    f16 hi = (f16)v;
                    copesp[(size_t)(half * 64 + pp) * 128 + d0 + j]      = hi;
                    copesp[(size_t)(half * 64 + pp) * 128 + 64 + d0 + j] = (f16)(v - (float)hi);
                }
            }
            __syncthreads();
        }
        return;
    }

    const float* W;
    switch (mat) {
        case 0: W = Wq;  break; case 1: W = Wk;  break; case 2: W = Wv;  break;
        case 3: W = Wqs; break; case 4: W = Wks; break; case 5: W = Wvs; break;
        case 6: W = Wqe; break; case 7: W = Wke; break; default: W = Wve; break;
    }
    const int k0  = kt * 64;
    #pragma unroll
    for (int i = 0; i < 4; ++i) {
        int g = tid + 256 * i;
        int k = g >> 4, c4 = g & 15;
        *(float4*)(xs + k * 68 + c4 * 4) = ((const float4*)W)[(size_t)(k0 + k) * 16 + c4];
    }
    __syncthreads();
    const int col = tid & 63, hf = tid >> 6;
    const int kk0 = hf * 16;
    U4 hi0, hi1, lo0, lo1;
    #pragma unroll
    for (int j = 0; j < 8; ++j) {
        float v0 = xs[(kk0 + j) * 68 + col];
        float v1 = xs[(kk0 + 8 + j) * 68 + col];
        hi0.h[j] = (f16)v0; lo0.h[j] = (f16)(v0 - (float)hi0.h[j]);
        hi1.h[j] = (f16)v1; lo1.h[j] = (f16)(v1 - (float)hi1.h[j]);
    }
    f16* dst = Wsp + (size_t)mat * 65536 + (size_t)col * 1024 + k0 + kk0;
    *(uint4*)(dst)       = hi0.u;
    *(uint4*)(dst + 8)   = hi1.u;
    *(uint4*)(dst + 512) = lo0.u;
    *(uint4*)(dst + 520) = lo1.u;
}

// ---------------------------------------------------------------------------
// k_proj: fused LayerNorm + q,k,v projections (unchanged from round 2).
// grid 288 x 256.
// ---------------------------------------------------------------------------
__global__ __launch_bounds__(256) void k_proj(
    const float* __restrict__ x, const f16* __restrict__ Wsp,
    const float* __restrict__ g0, const float* __restrict__ b0,
    const float* __restrict__ gs, const float* __restrict__ bs,
    const float* __restrict__ ge, const float* __restrict__ be,
    f16* __restrict__ qsp, f16* __restrict__ ksp, f16* __restrict__ vhT)
{
    __shared__ f16 As[32 * 136];
    __shared__ f16 Bs[3 * 64 * 136];
    __shared__ float mean_s[32], rstd_s[32];
    const int tid  = threadIdx.x;
    const int row0 = blockIdx.x * 32;
    const int rseq = row0 % L_;
    const int seg  = (rseq < S_) ? 0 : (rseq >= L_ - S_) ? 2 : 1;
    const int mat0 = (seg == 0) ? 3 : (seg == 2) ? 6 : 0;
    const float* gg = (seg == 0) ? gs : (seg == 2) ? ge : g0;
    const float* bb = (seg == 0) ? bs : (seg == 2) ? be : b0;

    {
        const int rr = tid >> 3, qq = tid & 7;
        const float4* xr = (const float4*)(x + (size_t)(row0 + rr) * DIN) + qq * 16;
        float s = 0.f, s2 = 0.f;
        #pragma unroll
        for (int i = 0; i < 16; ++i) {
            float4 v = xr[i];
            s  += v.x + v.y + v.z + v.w;
            s2 += v.x * v.x + v.y * v.y + v.z * v.z + v.w * v.w;
        }
        s  += __shfl_xor(s, 1);  s  += __shfl_xor(s, 2);  s  += __shfl_xor(s, 4);
        s2 += __shfl_xor(s2, 1); s2 += __shfl_xor(s2, 2); s2 += __shfl_xor(s2, 4);
        if (qq == 0) {
            float mean = s * (1.f / DIN);
            mean_s[rr] = mean;
            rstd_s[rr] = rsqrtf(s2 * (1.f / DIN) - mean * mean + 1e-5f);
        }
    }

    const int w = tid >> 6, lane = tid & 63;
    const int cl = lane & 15, quad = lane >> 4;
    const int r0 = 16 * (w >> 1), c0 = 32 * (w & 1);

    f32x4 acc[3][2];
    #pragma unroll
    for (int m = 0; m < 3; ++m)
        #pragma unroll
        for (int j = 0; j < 2; ++j) acc[m][j] = 0.f;

    for (int kc = 0; kc < DIN; kc += 64) {
        __syncthreads();
        {
            int r = tid >> 3, c8 = tid & 7;
            const float* xp = x + (size_t)(row0 + r) * DIN + kc + c8 * 8;
            float4 a0 = *(const float4*)xp;
            float4 a1 = *(const float4*)(xp + 4);
            float4 gA = *(const float4*)(gg + kc + c8 * 8);
            float4 gB = *(const float4*)(gg + kc + c8 * 8 + 4);
            float4 bA = *(const float4*)(bb + kc + c8 * 8);
            float4 bB = *(const float4*)(bb + kc + c8 * 8 + 4);
            float mean = mean_s[r], rstd = rstd_s[r];
            float n[8];
            n[0] = (a0.x - mean) * rstd * gA.x + bA.x;
            n[1] = (a0.y - mean) * rstd * gA.y + bA.y;
            n[2] = (a0.z - mean) * rstd * gA.z + bA.z;
            n[3] = (a0.w - mean) * rstd * gA.w + bA.w;
            n[4] = (a1.x - mean) * rstd * gB.x + bB.x;
            n[5] = (a1.y - mean) * rstd * gB.y + bB.y;
            n[6] = (a1.z - mean) * rstd * gB.z + bB.z;
            n[7] = (a1.w - mean) * rstd * gB.w + bB.w;
            U4 hi, lo;
            #pragma unroll
            for (int j = 0; j < 8; ++j) {
                hi.h[j] = (f16)n[j];
                lo.h[j] = (f16)(n[j] - (float)hi.h[j]);
            }
            *(uint4*)(As + r * 136 + c8 * 8)      = hi.u;
            *(uint4*)(As + r * 136 + 64 + c8 * 8) = lo.u;
        }
        #pragma unroll
        for (int i = 0; i < 6; ++i) {
            int g = tid + 256 * i;
            int mm = g >> 9, rem = g & 511;
            int col = rem >> 3, c8 = rem & 7;
            const f16* src = Wsp + (size_t)(mat0 + mm) * 65536 + (size_t)col * 1024 + kc + c8 * 8;
            f16* dst = Bs + mm * 8704 + col * 136 + c8 * 8;
            *(uint4*)(dst)      = *(const uint4*)(src);
            *(uint4*)(dst + 64) = *(const uint4*)(src + 512);
        }
        __syncthreads();
        #pragma unroll
        for (int h = 0; h < 2; ++h) {
            half8 ah, al;
            {
                const f16* base = As + (r0 + cl) * 136 + h * 32 + quad * 8;
                ah = *(const half8*)(base);
                al = *(const half8*)(base + 64);
            }
            #pragma unroll
            for (int m = 0; m < 3; ++m)
                #pragma unroll
                for (int cs = 0; cs < 2; ++cs) {
                    const f16* base = Bs + m * 8704 + (c0 + 16 * cs + cl) * 136 + h * 32 + quad * 8;
                    half8 bh = *(const half8*)(base);
                    half8 bl = *(const half8*)(base + 64);
                    acc[m][cs] = __builtin_amdgcn_mfma_f32_16x16x32_f16(ah, bh, acc[m][cs], 0, 0, 0);
                    acc[m][cs] = __builtin_amdgcn_mfma_f32_16x16x32_f16(ah, bl, acc[m][cs], 0, 0, 0);
                    acc[m][cs] = __builtin_amdgcn_mfma_f32_16x16x32_f16(al, bh, acc[m][cs], 0, 0, 0);
                }
        }
    }

    const int bI = row0 / L_;
    const int rb = row0 - bI * L_;
    #pragma unroll
    for (int m = 0; m < 3; ++m) {
        f16* sp = (m == 0) ? qsp : ksp;
        #pragma unroll
        for (int cs = 0; cs < 2; ++cs)
            #pragma unroll
            for (int r = 0; r < 4; ++r) {
                int lrow = r0 + quad * 4 + r;
                int col  = c0 + 16 * cs + cl;
                float v  = acc[m][cs][r];
                size_t grow = (size_t)(row0 + lrow);
                if (m < 2) {
                    f16 hv = (f16)v;
                    sp[grow * 128 + col]      = hv;
                    sp[grow * 128 + 64 + col] = (f16)(v - (float)hv);
                } else {
                    vhT[(size_t)(bI * 64 + col) * L_ + rb + lrow] = (f16)v;
                }
            }
    }
}

// ---------------------------------------------------------------------------
// k_fmid: fused mid-row attention. One block = 32 q-rows; 512 threads
// (8 waves: 2 row-groups x 4 col-quarters). Column tiles processed in
// REVERSE order so the CoPE suffix-sum is a running accumulator R.
// Per tile: dots (split-fp16 MFMA) -> sigma -> in-tile suffix -> pos/bias
// -> online softmax -> PV MFMA. Writes out directly. No intermediates.
// ---------------------------------------------------------------------------
__global__ __launch_bounds__(512) void k_fmid(
    const f16* __restrict__ qsp, const f16* __restrict__ ksp,
    const f16* __restrict__ vhT, const f16* __restrict__ copesp,
    float* __restrict__ out)
{
    __shared__ f16 Qs[32 * 136];      // q rows, hi|lo
    __shared__ f16 Ks[128 * 136];     // key rows, hi|lo (rows 64.. alias Ps)
    __shared__ f16 Vt[64 * 136];      // V^T: [vcol][k]
    __shared__ float li[32 * 132];    // [row][pos 0..127]
    __shared__ float Tq[4][32], Tm[4][32], Ll[4][32];
    f16* const Ps = Ks + 64 * 136;    // P tile fp16, aliases Ks rows 64..95

    const int tid = threadIdx.x;
    const int blk = blockIdx.x;
    const int b = blk >> 6, strip = blk & 63;
    const int q0 = strip * 32;
    const size_t rowbase = (size_t)b * L_ + S_ + q0;
    const int w = tid >> 6, lane = tid & 63;
    const int cl = lane & 15, quad = lane >> 4;
    const int g = w >> 2, ch = w & 3;
    const int tmax = ((q0 + 31) >> 7) + 1;

    // stage Q (once)
    {
        int r = tid >> 4, c = tid & 15;
        *(uint4*)(Qs + r * 136 + c * 8) = *(const uint4*)(qsp + (rowbase + r) * 128 + c * 8);
    }
    __syncthreads();

    // li = q . cope  via split-fp16 MFMA (wave: rows 16g, pcols 32ch)
    {
        f32x4 accli[2];
        accli[0] = 0.f; accli[1] = 0.f;
        #pragma unroll
        for (int h = 0; h < 2; ++h) {
            const f16* abase = Qs + (16 * g + cl) * 136 + h * 32 + quad * 8;
            half8 ah = *(const half8*)(abase);
            half8 al = *(const half8*)(abase + 64);
            #pragma unroll
            for (int cf = 0; cf < 2; ++cf) {
                const f16* bbase = copesp + (size_t)(32 * ch + 16 * cf + cl) * 128 + h * 32 + quad * 8;
                half8 bh = *(const half8*)(bbase);
                half8 bl = *(const half8*)(bbase + 64);
                accli[cf] = __builtin_amdgcn_mfma_f32_16x16x32_f16(ah, bh, accli[cf], 0, 0, 0);
                accli[cf] = __builtin_amdgcn_mfma_f32_16x16x32_f16(ah, bl, accli[cf], 0, 0, 0);
                accli[cf] = __builtin_amdgcn_mfma_f32_16x16x32_f16(al, bh, accli[cf], 0, 0, 0);
            }
        }
        #pragma unroll
        for (int cf = 0; cf < 2; ++cf)
            #pragma unroll
            for (int r = 0; r < 4; ++r)
                li[(16 * g + quad * 4 + r) * 132 + 32 * ch + 16 * cf + cl] = accli[cf][r];
    }

    float R[4]  = {0.f, 0.f, 0.f, 0.f};
    float m_run[4] = {NEGINF, NEGINF, NEGINF, NEGINF};
    float l_run[4] = {0.f, 0.f, 0.f, 0.f};
    f32x4 accO = 0.f;

    for (int t = 16; t >= 0; --t) {
        const bool mid    = (t >= 1);
        const bool causal = (t <= tmax);
        const int kbase   = mid ? (S_ + 128 * (t - 1)) : 0;

        __syncthreads();                         // A: prev tile consumed
        #pragma unroll
        for (int i = 0; i < 4; ++i) {            // stage K tile (128 rows)
            int gi = tid + 512 * i;
            int r = gi >> 4, c = gi & 15;
            *(uint4*)(Ks + r * 136 + c * 8) =
                *(const uint4*)(ksp + ((size_t)b * L_ + kbase + r) * 128 + c * 8);
        }
        if (causal) {
            #pragma unroll
            for (int i = 0; i < 2; ++i) {        // stage V^T tile (64 vcols)
                int gi = tid + 512 * i;
                int vc = gi >> 4, c = gi & 15;
                *(uint4*)(Vt + vc * 136 + c * 8) =
                    *(const uint4*)(vhT + (size_t)(b * 64 + vc) * L_ + kbase + c * 8);
            }
        }
        __syncthreads();                         // B

        // dots: wave computes rows 16g..+15, tile cols 32ch..+31
        f32x4 acc[2];
        acc[0] = 0.f; acc[1] = 0.f;
        #pragma unroll
        for (int h = 0; h < 2; ++h) {
            const f16* abase = Qs + (16 * g + cl) * 136 + h * 32 + quad * 8;
            half8 ah = *(const half8*)(abase);
            half8 al = *(const half8*)(abase + 64);
            #pragma unroll
            for (int cf = 0; cf < 2; ++cf) {
                const f16* bbase = Ks + (32 * ch + 16 * cf + cl) * 136 + h * 32 + quad * 8;
                half8 bh = *(const half8*)(bbase);
                half8 bl = *(const half8*)(bbase + 64);
                acc[cf] = __builtin_amdgcn_mfma_f32_16x16x32_f16(ah, bh, acc[cf], 0, 0, 0);
                acc[cf] = __builtin_amdgcn_mfma_f32_16x16x32_f16(ah, bl, acc[cf], 0, 0, 0);
                acc[cf] = __builtin_amdgcn_mfma_f32_16x16x32_f16(al, bh, acc[cf], 0, 0, 0);
            }
        }

        float sfx[2][4], F1r[4];
        float hq[4], ttot[4];
        if (mid) {
            // gates + in-tile suffix (inclusive) across the 16-lane groups
            #pragma unroll
            for (int cf = 0; cf < 2; ++cf)
                #pragma unroll
                for (int r = 0; r < 4; ++r)
                    sfx[cf][r] = 1.f / (1.f + __expf(-acc[cf][r]));
            #pragma unroll
            for (int off = 1; off < 16; off <<= 1) {
                #pragma unroll
                for (int cf = 0; cf < 2; ++cf)
                    #pragma unroll
                    for (int r = 0; r < 4; ++r) {
                        float u = __shfl_down(sfx[cf][r], off, 16);
                        if (cl + off < 16) sfx[cf][r] += u;
                    }
            }
            float F0r[4];
            #pragma unroll
            for (int r = 0; r < 4; ++r) {
                F0r[r] = __shfl(sfx[0][r], 0, 16);
                F1r[r] = __shfl(sfx[1][r], 0, 16);
            }
            if (cl == 0) {
                #pragma unroll
                for (int r = 0; r < 4; ++r)
                    Tq[ch][16 * g + quad * 4 + r] = F0r[r] + F1r[r];
            }
            __syncthreads();                     // C: quarter totals ready
            #pragma unroll
            for (int r = 0; r < 4; ++r) {
                int row = 16 * g + quad * 4 + r;
                float t0 = Tq[0][row], t1 = Tq[1][row], t2 = Tq[2][row], t3 = Tq[3][row];
                ttot[r] = t0 + t1 + t2 + t3;
                hq[r] = (ch == 0) ? (t1 + t2 + t3) : (ch == 1) ? (t2 + t3) : (ch == 2) ? t3 : 0.f;
            }
        }

        if (causal) {
            float p0[2][4];
            float ml[4] = {NEGINF, NEGINF, NEGINF, NEGINF};
            #pragma unroll
            for (int cf = 0; cf < 2; ++cf)
                #pragma unroll
                for (int r = 0; r < 4; ++r) {
                    int row = 16 * g + quad * 4 + r;
                    int q = q0 + row;
                    float sc;
                    if (mid) {
                        int mcol = 128 * (t - 1) + 32 * ch + 16 * cf + cl;
                        float run = sfx[cf][r] + ((cf == 0) ? F1r[r] : 0.f) + hq[r] + R[r];
                        float pos = fminf(run, 127.f);
                        float pfl = floorf(pos);
                        int ic = (int)ceilf(pos), ifl = (int)pfl;
                        float wf = pos - pfl;
                        float bias = li[row * 132 + ic] * wf + li[row * 132 + ifl] * (1.f - wf);
                        sc = (mcol <= q) ? acc[cf][r] * SCALE + bias : NEGINF;
                    } else {
                        sc = acc[cf][r] * SCALE;
                    }
                    p0[cf][r] = sc;
                    ml[r] = fmaxf(ml[r], sc);
                }
            #pragma unroll
            for (int off = 1; off < 16; off <<= 1)
                #pragma unroll
                for (int r = 0; r < 4; ++r)
                    ml[r] = fmaxf(ml[r], __shfl_xor(ml[r], off, 16));
            if (cl == 0) {
                #pragma unroll
                for (int r = 0; r < 4; ++r)
                    Tm[ch][16 * g + quad * 4 + r] = ml[r];
            }
            __syncthreads();                     // D: tile maxima ready
            float rs_[4];
            #pragma unroll
            for (int r = 0; r < 4; ++r) {
                int row = 16 * g + quad * 4 + r;
                float mn = fmaxf(fmaxf(Tm[0][row], Tm[1][row]), fmaxf(Tm[2][row], Tm[3][row]));
                mn = fmaxf(fmaxf(mn, m_run[r]), -1e28f);
                rs_[r] = __expf(m_run[r] - mn);
                m_run[r] = mn;
            }
            float ll[4] = {0.f, 0.f, 0.f, 0.f};
            #pragma unroll
            for (int cf = 0; cf < 2; ++cf)
                #pragma unroll
                for (int r = 0; r < 4; ++r) {
                    int row = 16 * g + quad * 4 + r;
                    float e = __expf(p0[cf][r] - m_run[r]);
                    ll[r] += e;
                    Ps[row * 136 + 32 * ch + 16 * cf + cl] = (f16)e;
                }
            #pragma unroll
            for (int off = 1; off < 16; off <<= 1)
                #pragma unroll
                for (int r = 0; r < 4; ++r)
                    ll[r] += __shfl_xor(ll[r], off, 16);
            if (cl == 0) {
                #pragma unroll
                for (int r = 0; r < 4; ++r)
                    Ll[ch][16 * g + quad * 4 + r] = ll[r];
            }
            #pragma unroll
            for (int r = 0; r < 4; ++r) accO[r] *= rs_[r];
            __syncthreads();                     // E: P tile + l parts ready
            #pragma unroll
            for (int r = 0; r < 4; ++r) {
                int row = 16 * g + quad * 4 + r;
                l_run[r] = l_run[r] * rs_[r] + Ll[0][row] + Ll[1][row] + Ll[2][row] + Ll[3][row];
            }
            #pragma unroll
            for (int kf = 0; kf < 4; ++kf) {
                half8 a  = *(const half8*)(Ps + (16 * g + cl) * 136 + kf * 32 + quad * 8);
                half8 bv = *(const half8*)(Vt + (16 * ch + cl) * 136 + kf * 32 + quad * 8);
                accO = __builtin_amdgcn_mfma_f32_16x16x32_f16(a, bv, accO, 0, 0, 0);
            }
        }

        if (mid) {
            #pragma unroll
            for (int r = 0; r < 4; ++r) R[r] += ttot[r];
        }
    }

    // epilogue: out = accO / l
    #pragma unroll
    for (int r = 0; r < 4; ++r) {
        int row = 16 * g + quad * 4 + r;
        int col = 16 * ch + cl;
        out[(rowbase + row) * DK + col] = accO[r] / l_run[r];
    }
}

// ---------------------------------------------------------------------------
// k_dotse: edge dots only (old k_dots, bx offset +64). grid (8,18) x 256.
// ---------------------------------------------------------------------------
__global__ __launch_bounds__(256) void k_dotse(
    const f16* __restrict__ qsp, const f16* __restrict__ ksp,
    float* __restrict__ De32)
{
    const int bx = blockIdx.x + 64, by = blockIdx.y;
    int ex = bx - 64;
    int b = ex >> 1;
    int half = ex & 1;
    if (half == 0 && by > 0) return;
    size_t qrow0 = (size_t)b * L_ + (half ? 2176 : 0);
    const int col0 = by * 128;
    const size_t krow0 = (size_t)b * L_ + col0;

    __shared__ f16 Qs[128 * 136];
    __shared__ f16 Ks[128 * 136];
    const int tid = threadIdx.x;

    #pragma unroll
    for (int i = 0; i < 8; ++i) {
        int g = tid + 256 * i;
        int r = g >> 4, c = g & 15;
        *(uint4*)(Qs + r * 136 + c * 8) = *(const uint4*)(qsp + (qrow0 + r) * 128 + c * 8);
        *(uint4*)(Ks + r * 136 + c * 8) = *(const uint4*)(ksp + (krow0 + r) * 128 + c * 8);
    }
    __syncthreads();

    const int w = tid >> 6, lane = tid & 63;
    const int cl = lane & 15, quad = lane >> 4;

    f32x4 acc[2][8];
    #pragma unroll
    for (int i = 0; i < 2; ++i)
        #pragma unroll
        for (int j = 0; j < 8; ++j) acc[i][j] = 0.f;

    #pragma unroll
    for (int h = 0; h < 2; ++h) {
        half8 ah[2], al[2];
        #pragma unroll
        for (int rs = 0; rs < 2; ++rs) {
            const f16* base = Qs + (32 * w + 16 * rs + cl) * 136 + h * 32 + quad * 8;
            ah[rs] = *(const half8*)(base);
            al[rs] = *(const half8*)(base + 64);
        }
        #pragma unroll
        for (int cq = 0; cq < 2; ++cq) {
            half8 bh[4], bl[4];
            #pragma unroll
            for (int cc = 0; cc < 4; ++cc) {
                const f16* base = Ks + (16 * (cq * 4 + cc) + cl) * 136 + h * 32 + quad * 8;
                bh[cc] = *(const half8*)(base);
                bl[cc] = *(const half8*)(base + 64);
            }
            #pragma unroll
            for (int rs = 0; rs < 2; ++rs)
                #pragma unroll
                for (int cc = 0; cc < 4; ++cc) {
                    int c = cq * 4 + cc;
                    acc[rs][c] = __builtin_amdgcn_mfma_f32_16x16x32_f16(ah[rs], bh[cc], acc[rs][c], 0, 0, 0);
                    acc[rs][c] = __builtin_amdgcn_mfma_f32_16x16x32_f16(ah[rs], bl[cc], acc[rs][c], 0, 0, 0);
                    acc[rs][c] = __builtin_amdgcn_mfma_f32_16x16x32_f16(al[rs], bh[cc], acc[rs][c], 0, 0, 0);
                }
        }
    }

    const int er0 = (bx - 64) * 128;
    #pragma unroll
    for (int rs = 0; rs < 2; ++rs)
        #pragma unroll
        for (int c = 0; c < 8; ++c)
            #pragma unroll
            for (int r = 0; r < 4; ++r) {
                int erow = er0 + 32 * w + 16 * rs + quad * 4 + r;
                int n    = col0 + 16 * c + cl;
                De32[(size_t)erow * LE + n] = acc[rs][c][r];
            }
}

// ---------------------------------------------------------------------------
// k_scane: edge softmax only. grid 1024 x 256.
// ---------------------------------------------------------------------------
__global__ __launch_bounds__(256) void k_scane(
    const float* __restrict__ De32, f16* __restrict__ Dep)
{
    __shared__ float wmax[4], wsum[4];
    const int tid = threadIdx.x;
    const int er  = blockIdx.x;
    const int lane = tid & 63, wid = tid >> 6;
    const int r  = er & 255;
    const int Q  = (r < 128) ? r : (2048 + r);
    const float* Er32 = De32 + (size_t)er * LE;
    f16* Er = Dep + (size_t)er * LE;

    float v[9];
    #pragma unroll
    for (int i = 0; i < 9; ++i) {
        int j = tid + 256 * i;
        float d = Er32[j];
        v[i] = (j <= Q) ? d * SCALE : NEGINF;
    }
    float mx = v[0];
    #pragma unroll
    for (int i = 1; i < 9; ++i) mx = fmaxf(mx, v[i]);
    #pragma unroll
    for (int off = 1; off < 64; off <<= 1) mx = fmaxf(mx, __shfl_xor(mx, off));
    if (lane == 0) wmax[wid] = mx;
    __syncthreads();
    mx = fmaxf(fmaxf(wmax[0], wmax[1]), fmaxf(wmax[2], wmax[3]));

    float lsum = 0.f;
    #pragma unroll
    for (int i = 0; i < 9; ++i) {
        v[i] = __expf(v[i] - mx);
        lsum += v[i];
    }
    #pragma unroll
    for (int off = 1; off < 64; off <<= 1) lsum += __shfl_xor(lsum, off);
    if (lane == 0) wsum[wid] = lsum;
    __syncthreads();
    float inv = 1.f / (wsum[0] + wsum[1] + wsum[2] + wsum[3]);

    #pragma unroll
    for (int i = 0; i < 9; ++i)
        Er[tid + 256 * i] = (f16)(v[i] * inv);
}

// ---------------------------------------------------------------------------
// k_pve: edge PV. grid (16, 4) x 256.
// ---------------------------------------------------------------------------
__global__ __launch_bounds__(256) void k_pve(
    const f16* __restrict__ Pedge, const f16* __restrict__ vhT,
    float* __restrict__ Oe)
{
    __shared__ f16 Ps[64 * 72];
    __shared__ f16 Vt[64 * 72];
    const int tid = threadIdx.x;
    const int ks  = blockIdx.y;

    int row0 = blockIdx.x * 64;
    int b = row0 >> 8;
    int r0 = row0 & 255;
    const f16* Pb = Pedge;
    const size_t pitch = LE;
    int Qmax = (r0 < 128) ? (r0 + 63) : (2048 + r0 + 63);
    int cmax = Qmax >> 6;
    float* outp = Oe + (size_t)ks * NEDGE * DK;

    const int c_beg = ks * 9;
    int c_end = c_beg + 9;
    if (c_end > 36) c_end = 36;
    if (c_end > cmax + 1) c_end = cmax + 1;

    const int w = tid >> 6, lane = tid & 63;
    const int cl = lane & 15, quad = lane >> 4;
    f32x4 acc[4];
    #pragma unroll
    for (int c = 0; c < 4; ++c) acc[c] = 0.f;

    for (int ch = c_beg; ch < c_end; ++ch) {
        __syncthreads();
        #pragma unroll
        for (int i = 0; i < 2; ++i) {
            int g = tid + 256 * i;
            int r = g >> 3, c = g & 7;
            *(uint4*)(Ps + r * 72 + c * 8) =
                *(const uint4*)(Pb + (size_t)(row0 + r) * pitch + ch * 64 + c * 8);
            *(uint4*)(Vt + r * 72 + c * 8) =
                *(const uint4*)(vhT + (size_t)(b * 64 + r) * L_ + ch * 64 + c * 8);
        }
        __syncthreads();
        #pragma unroll
        for (int h = 0; h < 2; ++h) {
            half8 a = *(const half8*)(Ps + (16 * w + cl) * 72 + h * 32 + quad * 8);
            #pragma unroll
            for (int c = 0; c < 4; ++c) {
                half8 bv = *(const half8*)(Vt + (16 * c + cl) * 72 + h * 32 + quad * 8);
                acc[c] = __builtin_amdgcn_mfma_f32_16x16x32_f16(a, bv, acc[c], 0, 0, 0);
            }
        }
    }
    #pragma unroll
    for (int c = 0; c < 4; ++c)
        #pragma unroll
        for (int r = 0; r < 4; ++r) {
            int mrow = row0 + 16 * w + quad * 4 + r;
            int n    = 16 * c + cl;
            outp[(size_t)mrow * DK + n] = acc[c][r];
        }
}

// ---------------------------------------------------------------------------
// k_mergee: sum 4 edge partials. grid 256 x 256.
// ---------------------------------------------------------------------------
__global__ __launch_bounds__(256) void k_mergee(
    const float* __restrict__ Oe, float* __restrict__ out)
{
    const int e2 = blockIdx.x * 256 + threadIdx.x;
    const int er = e2 >> 6, c = e2 & 63;
    const int b  = er >> 8, r = er & 255;
    const int gQ = (r < 128) ? r : (2048 + r);
    const int NP = NEDGE * DK;
    float s = Oe[e2] + Oe[e2 + NP] + Oe[e2 + 2 * NP] + Oe[e2 + 3 * NP];
    out[((size_t)b * L_ + gQ) * DK + c] = s;
}

// ---------------------------------------------------------------------------
extern "C" void kernel_launch(void* const* d_in, const int* in_sizes, int n_in,
                              void* d_out, int out_size, void* d_ws, size_t ws_size,
                              hipStream_t stream)
{
    const float* x    = (const float*)d_in[0];
    const float* Wq   = (const float*)d_in[1];
    const float* Wk   = (const float*)d_in[2];
    const float* Wv   = (const float*)d_in[3];
    const float* Wqs  = (const float*)d_in[4];
    const float* Wks  = (const float*)d_in[5];
    const float* Wvs  = (const float*)d_in[6];
    const float* Wqe  = (const float*)d_in[7];
    const float* Wke  = (const float*)d_in[8];
    const float* Wve  = (const float*)d_in[9];
    const float* g0   = (const float*)d_in[10];
    const float* b0   = (const float*)d_in[11];
    const float* gs   = (const float*)d_in[12];
    const float* bs   = (const float*)d_in[13];
    const float* ge   = (const float*)d_in[14];
    const float* be   = (const float*)d_in[15];
    const float* cope = (const float*)d_in[16];

    const size_t NR = (size_t)B_ * L_;                 // 9216 rows
    f16*   qsp    = (f16*)d_ws;                        // NR*128
    f16*   ksp    = qsp + NR * 128;                    // NR*128
    f16*   vhT    = ksp + NR * 128;                    // NR*64
    f16*   Wsp    = vhT + NR * 64;                     // 9*65536
    f16*   copesp = Wsp + (size_t)9 * 65536;           // 128*128
    float* De32   = (float*)(copesp + 16384);          // NEDGE*LE f32
    float* Oe     = De32 + (size_t)NEDGE * LE;         // 4*NEDGE*64 f32
    f16*   Dep    = (f16*)(Oe + (size_t)4 * NEDGE * DK); // NEDGE*LE f16
    float* out    = (float*)d_out;

    k_wsplit<<<dim3(8, 10), 256, 0, stream>>>(Wq, Wk, Wv, Wqs, Wks, Wvs,
                                              Wqe, Wke, Wve, cope, Wsp, copesp);
    k_proj<<<288, 256, 0, stream>>>(x, Wsp, g0, b0, gs, bs, ge, be,
                                    qsp, ksp, vhT);
    k_dotse<<<dim3(8, 18), 256, 0, stream>>>(qsp, ksp, De32);
    k_fmid<<<256, 512, 0, stream>>>(qsp, ksp, vhT, copesp, out);
    k_scane<<<NEDGE, 256, 0, stream>>>(De32, Dep);
    k_pve<<<dim3(16, 4), 256, 0, stream>>>(Dep, vhT, Oe);
    k_mergee<<<256, 256, 0, stream>>>(Oe, out);
}